// Round 4
// baseline (1026.956 us; speedup 1.0000x reference)
//
#include <hip/hip_runtime.h>
#include <hip/hip_bf16.h>

#define C_CH 32
#define K_TAPS 27
#define CONV_GRID 8192

typedef short bf16x8 __attribute__((ext_vector_type(8)));
typedef float f32x4 __attribute__((ext_vector_type(4)));

// ---------------------------------------------------------------------------
// Kernel 0: convert weights f32 -> bf16 MFMA B-fragments (layout verified in
// round 3). Element t: e=t&7, lane=(t>>3)&63, half=(t>>9)&1, tap=t>>10.
// B[k=ci][n=j]: ci=(lane>>4)*8+e, j=half*16+(lane&15).
// ---------------------------------------------------------------------------
__global__ __launch_bounds__(256) void convert_weights_kernel(
    const float* __restrict__ wt, short* __restrict__ wbf)
{
    int t = blockIdx.x * 256 + threadIdx.x;
    if (t < K_TAPS * 1024) {
        int e = t & 7, l = (t >> 3) & 63, half = (t >> 9) & 1, k = t >> 10;
        int ci = (l >> 4) * 8 + e;
        int j  = half * 16 + (l & 15);
        union { __hip_bfloat16 h; short s; } u;
        u.h = __float2bfloat16(wt[k * 1024 + ci * 32 + j]);
        wbf[t] = u.s;
    }
}

// ---------------------------------------------------------------------------
// Kernel 1: sparse conv via MFMA. One wave = 16 voxels.
// UNCONDITIONAL 27-tap straight-line body: every tap's gather is issued
// (safe index 0 when inactive) and masked afterwards with cndmask -> the
// compiler can pipeline many gathers in flight (counted vmcnt), instead of
// one-latency-per-tap serialization.
// ---------------------------------------------------------------------------
__global__ __launch_bounds__(256) void conv_mfma_kernel(
    const float* __restrict__ feat,   // [N, 32] f32
    const short* __restrict__ wbf,    // bf16 B-fragments [27][2][64][8]
    const int*   __restrict__ nbr,    // [N, 27]
    float* __restrict__ out,          // [N, 32] (pre-BN)
    float* __restrict__ stats,        // [0..31] sum, [32..63] sumsq
    int n)
{
    __shared__ float bsum[C_CH];
    __shared__ float bsq[C_CH];
    const int tid = threadIdx.x;
    if (tid < C_CH) { bsum[tid] = 0.0f; bsq[tid] = 0.0f; }
    __syncthreads();

    const int l   = tid & 63;
    const int wv  = tid >> 6;
    const int row = l & 15;        // A-row / voxel slot within batch
    const int kq  = l >> 4;        // k-chunk 0..3
    const int n_batches   = (n + 15) >> 4;
    const int wave_gid    = blockIdx.x * 4 + wv;
    const int total_waves = CONV_GRID * 4;

    float ps0 = 0.0f, ps1 = 0.0f, pq0 = 0.0f, pq1 = 0.0f;

    for (int b = wave_gid; b < n_batches; b += total_waves) {
        const int vbase = b << 4;
        const int myv   = vbase + row;
        const bool rowok = myv < n;

        // prefetch all 27 neighbor indices (independent, coalesced)
        int idxs[K_TAPS];
        #pragma unroll
        for (int k = 0; k < K_TAPS; ++k)
            idxs[k] = rowok ? nbr[(size_t)myv * K_TAPS + k] : -1;

        f32x4 acc0 = {0.f, 0.f, 0.f, 0.f};
        f32x4 acc1 = {0.f, 0.f, 0.f, 0.f};

        #pragma unroll
        for (int k = 0; k < K_TAPS; ++k) {
            const int  idx   = idxs[k];
            const bool valid = idx >= 0;
            const int  safe  = valid ? idx : 0;

            const float4* fp =
                (const float4*)(feat + (size_t)safe * C_CH + kq * 8);
            float4 f0 = fp[0];
            float4 f1 = fp[1];

            union { bf16x8 v; __hip_bfloat162 h[4]; } au;
            au.h[0] = __float22bfloat162_rn(make_float2(f0.x, f0.y));
            au.h[1] = __float22bfloat162_rn(make_float2(f0.z, f0.w));
            au.h[2] = __float22bfloat162_rn(make_float2(f1.x, f1.y));
            au.h[3] = __float22bfloat162_rn(make_float2(f1.z, f1.w));
            const bf16x8 zero = {0, 0, 0, 0, 0, 0, 0, 0};
            bf16x8 a = valid ? au.v : zero;     // 4x v_cndmask_b32

            bf16x8 b0 = *(const bf16x8*)(wbf + (((k * 2 + 0) * 64 + l) << 3));
            bf16x8 b1 = *(const bf16x8*)(wbf + (((k * 2 + 1) * 64 + l) << 3));

            acc0 = __builtin_amdgcn_mfma_f32_16x16x32_bf16(a, b0, acc0, 0, 0, 0);
            acc1 = __builtin_amdgcn_mfma_f32_16x16x32_bf16(a, b1, acc1, 0, 0, 0);
        }

        // C/D layout: col = lane&15, row = (lane>>4)*4 + r
        #pragma unroll
        for (int r = 0; r < 4; ++r) {
            const int orow = vbase + kq * 4 + r;
            if (orow < n) {
                const float v0 = acc0[r];
                const float v1 = acc1[r];
                out[(size_t)orow * C_CH + (l & 15)]      = v0;
                out[(size_t)orow * C_CH + 16 + (l & 15)] = v1;
                ps0 += v0; pq0 += v0 * v0;
                ps1 += v1; pq1 += v1 * v1;
            }
        }
    }

    // lanes {l, l^16, l^32, l^48} hold the same channel pair -> combine
    ps0 += __shfl_xor(ps0, 16); ps0 += __shfl_xor(ps0, 32);
    ps1 += __shfl_xor(ps1, 16); ps1 += __shfl_xor(ps1, 32);
    pq0 += __shfl_xor(pq0, 16); pq0 += __shfl_xor(pq0, 32);
    pq1 += __shfl_xor(pq1, 16); pq1 += __shfl_xor(pq1, 32);

    if (l < 16) {
        atomicAdd(&bsum[l],      ps0);
        atomicAdd(&bsum[16 + l], ps1);
        atomicAdd(&bsq[l],       pq0);
        atomicAdd(&bsq[16 + l],  pq1);
    }
    __syncthreads();
    if (tid < C_CH) {
        atomicAdd(&stats[tid],        bsum[tid]);
        atomicAdd(&stats[C_CH + tid], bsq[tid]);
    }
}

// ---------------------------------------------------------------------------
// Kernel 2: BN finalize (per-block, into LDS) + apply + ReLU, float4 in-place
// ---------------------------------------------------------------------------
__global__ __launch_bounds__(256) void bn_apply_kernel(
    float* __restrict__ out,
    const float* __restrict__ stats,
    const float* __restrict__ gamma,
    const float* __restrict__ beta,
    float inv_n, int total4)
{
    __shared__ float s_sc[C_CH];
    __shared__ float s_sh[C_CH];
    if (threadIdx.x < C_CH) {
        int j = threadIdx.x;
        float mean = stats[j] * inv_n;
        float var  = stats[C_CH + j] * inv_n - mean * mean;
        float sc   = gamma[j] * rsqrtf(var + 1e-4f);
        s_sc[j] = sc;
        s_sh[j] = beta[j] - mean * sc;
    }
    __syncthreads();

    int e = blockIdx.x * 256 + threadIdx.x;
    if (e < total4) {
        float4 v = ((float4*)out)[e];
        int c = (e & 7) * 4;
        v.x = fmaxf(fmaf(v.x, s_sc[c + 0], s_sh[c + 0]), 0.0f);
        v.y = fmaxf(fmaf(v.y, s_sc[c + 1], s_sh[c + 1]), 0.0f);
        v.z = fmaxf(fmaf(v.z, s_sc[c + 2], s_sh[c + 2]), 0.0f);
        v.w = fmaxf(fmaf(v.w, s_sc[c + 3], s_sh[c + 3]), 0.0f);
        ((float4*)out)[e] = v;
    }
}

extern "C" void kernel_launch(void* const* d_in, const int* in_sizes, int n_in,
                              void* d_out, int out_size, void* d_ws, size_t ws_size,
                              hipStream_t stream) {
    const float* feat  = (const float*)d_in[0];   // [N, 32]
    const float* wt    = (const float*)d_in[1];   // [27, 32, 32]
    const float* gamma = (const float*)d_in[2];   // [32]
    const float* beta  = (const float*)d_in[3];   // [32]
    const int*   nbr   = (const int*)d_in[4];     // [N, 27]

    float* out   = (float*)d_out;
    float* stats = (float*)d_ws;                  // 64 f32: sum, sumsq
    short* wbf   = (short*)(stats + 2 * C_CH);    // 27648 bf16 weight fragments

    const int n = in_sizes[0] / C_CH;

    hipMemsetAsync(stats, 0, 2 * C_CH * sizeof(float), stream);

    convert_weights_kernel<<<(K_TAPS * 1024 + 255) / 256, 256, 0, stream>>>(wt, wbf);

    conv_mfma_kernel<<<CONV_GRID, 256, 0, stream>>>(feat, wbf, nbr, out, stats, n);

    const int total4 = n * C_CH / 4;
    bn_apply_kernel<<<(total4 + 255) / 256, 256, 0, stream>>>(
        out, stats, gamma, beta, 1.0f / (float)n, total4);
}